// Round 10
// baseline (201.823 us; speedup 1.0000x reference)
//
#include <hip/hip_runtime.h>

typedef unsigned short u16;
typedef unsigned int   u32;
typedef __attribute__((ext_vector_type(8))) short bf16x8;
typedef __attribute__((ext_vector_type(4))) short s16x4;
typedef __attribute__((ext_vector_type(4))) float f32x4;

#define MFMA16(a,b,c) __builtin_amdgcn_mfma_f32_16x16x32_bf16((a),(b),(c),0,0,0)

// soft barriers: raw s_barrier + counted waits
#define SOFT_BAR_LG() do{ asm volatile("s_waitcnt lgkmcnt(0)" ::: "memory"); \
  __builtin_amdgcn_s_barrier(); __builtin_amdgcn_sched_barrier(0); }while(0)
#define SOFT_BAR_VM(N) do{ asm volatile("s_waitcnt vmcnt(" #N ") lgkmcnt(0)" ::: "memory"); \
  __builtin_amdgcn_s_barrier(); __builtin_amdgcn_sched_barrier(0); }while(0)

__device__ __forceinline__ float bf2f(u16 u){ return __uint_as_float(((u32)u)<<16); }
__device__ __forceinline__ u16 f2bf(float f){
  u32 u = __float_as_uint(f);
  return (u16)((u + 0x7fffu + ((u>>16)&1u)) >> 16);
}
__device__ __forceinline__ u32 encf(float f){ u32 u=__float_as_uint(f); return (u&0x80000000u)? ~u : (u|0x80000000u); }
__device__ __forceinline__ float decf(u32 u){ return (u&0x80000000u)? __uint_as_float(u&0x7fffffffu) : __uint_as_float(~u); }

__device__ __forceinline__ void async_lds16(u16* lds, const u16* g){
  __builtin_amdgcn_global_load_lds((const __attribute__((address_space(1))) void*)g,
                                   (__attribute__((address_space(3))) void*)lds,
                                   16, 0, 0);
}

// stage ROWS x 64 bf16 from global into LDS padded to 72/row
template<int ROWS>
__device__ __forceinline__ void stage64(u16* dst, const u16* src, int srcStride, int tid){
  #pragma unroll
  for (int u=tid; u<ROWS*8; u+=256){
    int r=u>>3, c=(u&7)<<3;
    *(int4*)&dst[r*72+c] = *(const int4*)&src[(size_t)r*srcStride + c];
  }
}

// ---------------- init ----------------
__global__ void k_init(u32* kmaxEnc, u16* projS,
                       const float* __restrict__ proj, const float* __restrict__ x, u16* __restrict__ xb){
  int i = blockIdx.x*blockDim.x + threadIdx.x;
  int st = gridDim.x*blockDim.x;
  for (int j=i; j<32; j+=st) kmaxEnc[j]=0u;
  const float dn = 0.35355339059327373f; // 64^-0.25
  for (int j=i; j<512*64; j+=st) projS[j] = f2bf(dn*proj[j]);
  for (int j=i; j<524288; j+=st){
    float4 a = *(const float4*)&x[(size_t)j*8];
    float4 b = *(const float4*)&x[(size_t)j*8+4];
    u16 tmp[8] = {f2bf(a.x),f2bf(a.y),f2bf(a.z),f2bf(a.w),
                  f2bf(b.x),f2bf(b.y),f2bf(b.z),f2bf(b.w)};
    *(int4*)&xb[(size_t)j*8] = *(const int4*)tmp;
  }
}

// ---------------- fp32 512x512 -> bf16 transpose, batched over 4 weights ----------------
__global__ __launch_bounds__(256) void k_trw(const float* s0, const float* s1, const float* s2, const float* s3,
                                             u16* d0, u16* d1, u16* d2, u16* d3){
  int z = blockIdx.z;
  const float* src = z==0?s0:(z==1?s1:(z==2?s2:s3));
  u16* dst         = z==0?d0:(z==1?d1:(z==2?d2:d3));
  __shared__ u16 t[32][34];
  int c0=blockIdx.x*32, r0=blockIdx.y*32;
  int tid=threadIdx.x;
  for (int u=tid; u<1024; u+=256){ int r=u>>5, c=u&31; t[r][c]=f2bf(src[(size_t)(r0+r)*512 + c0+c]); }
  __syncthreads();
  for (int u=tid; u<1024; u+=256){ int c=u>>5, r=u&31; dst[(size_t)(c0+c)*512 + r0+r]=t[r][c]; }
}

// ---------------- v -> vT[bh][64][2048] ----------------
__global__ __launch_bounds__(256) void k_trv(const u16* __restrict__ v, u16* __restrict__ vT){
  int bh = blockIdx.z; int b=bh>>3, h=bh&7;
  int d0 = blockIdx.x*32, n0 = blockIdx.y*32;
  __shared__ u16 t[32][34];
  int tid=threadIdx.x;
  const u16* s = v + (size_t)(b*2048)*512 + h*64;
  for (int u=tid; u<1024; u+=256){ int r=u>>5, c=u&31; t[r][c]=s[(size_t)(n0+r)*512 + d0+c]; }
  __syncthreads();
  u16* d = vT + (size_t)bh*64*2048;
  for (int u=tid; u<1024; u+=256){ int c=u>>5, r=u&31; d[(size_t)(d0+c)*2048 + n0+r]=t[r][c]; }
}

// ---------------- vsum ----------------
__global__ __launch_bounds__(256) void k_vsum(const u16* __restrict__ vB, float* __restrict__ vsum){
  int bh=blockIdx.x; int b=bh>>3, h=bh&7;
  int tid=threadIdx.x; int d=tid&63, part=tid>>6;
  const u16* src = vB + (size_t)(b*2048 + part*512)*512 + h*64 + d;
  float s=0.f;
  for (int n=0;n<512;++n) s += bf2f(src[(size_t)n*512]);
  __shared__ float red[256];
  red[tid]=s; __syncthreads();
  if (part==0) vsum[bh*64+d]=red[d]+red[64+d]+red[128+d]+red[192+d];
}

// ---------------- per-bh sums ----------------
__global__ __launch_bounds__(256) void k_sums(const u16* __restrict__ ctxT, const float* __restrict__ kcs,
                                              float* __restrict__ ctxsum, float* __restrict__ kcssum){
  int bh = blockIdx.x;
  int tid = threadIdx.x;
  int d = tid&63, part = tid>>6;
  const u16* src = ctxT + (size_t)bh*64*512 + (size_t)d*512 + part*128;
  float s=0.f;
  for (int m=0;m<128;m+=8){
    bf16x8 v = *(const bf16x8*)&src[m];
    #pragma unroll
    for (int j=0;j<8;++j) s += bf2f((u16)v[j]);
  }
  __shared__ float red[256];
  __shared__ float red2[256];
  red[tid]=s;
  float t=0.f;
  for (int u=tid;u<512;u+=256) t += kcs[(size_t)bh*512+u];
  red2[tid]=t;
  __syncthreads();
  if (part==0) ctxsum[bh*64+d] = red[d]+red[64+d]+red[128+d]+red[192+d];
  if (tid<64){
    float a=red2[tid]+red2[tid+64]+red2[tid+128]+red2[tid+192];
    #pragma unroll
    for (int m2=1;m2<64;m2<<=1) a += __shfl_xor(a,m2,64);
    if (tid==0) kcssum[bh]=a;
  }
}

// ---------------- GEMM, 2-deep async pipeline: O = A @ BT^T + bias ----------------
template<bool OF32>
__global__ __launch_bounds__(256) void k_gemm2(const u16* __restrict__ A,
    const u16* BT0, const u16* BT1, const u16* BT2,
    const float* b0, const float* b1, const float* b2,
    void* O0, void* O1, void* O2)
{
  int z = blockIdx.z;
  const u16* BT    = z==0?BT0:(z==1?BT1:BT2);
  const float* bias= z==0?b0 :(z==1?b1 :b2 );
  void* Ov         = z==0?O0 :(z==1?O1 :O2 );
  int bm = blockIdx.x*128, bn = blockIdx.y*64;
  __shared__ u16 sA[2][128*64];
  __shared__ u16 sB[2][64*64];
  int tid=threadIdx.x, w=tid>>6, lane=tid&63;
  int lr = lane>>3, lc = (lane&7)*8;
  f32x4 acc[8] = {};
  auto stage=[&](int bf, int koff){
    #pragma unroll
    for (int i=0;i<4;++i){
      int idx = w*4+i;
      async_lds16(&sA[bf][idx*512], A + (size_t)(bm + idx*8 + lr)*512 + koff + lc);
    }
    #pragma unroll
    for (int i=0;i<2;++i){
      int idx = w*2+i;
      async_lds16(&sB[bf][idx*512], BT + (size_t)(bn + idx*8 + lr)*512 + koff + lc);
    }
  };
  stage(0, 0);
  int fr = lane&15, kb=(lane>>4)*8;
  for (int kk=0; kk<8; ++kk){
    int cur = kk&1;
    if (kk<7) stage(cur^1, (kk+1)*64);
    if (kk<7) { SOFT_BAR_VM(6); } else { SOFT_BAR_VM(0); }
    #pragma unroll
    for (int rt=0; rt<2; ++rt){
      int ar = (w*2+rt)*16 + fr;
      #pragma unroll
      for (int ct=0; ct<4; ++ct){
        int br = ct*16 + fr;
        #pragma unroll
        for (int kc=0; kc<2; ++kc){
          bf16x8 av = *(const bf16x8*)&sA[cur][ar*64 + kc*32 + kb];
          bf16x8 bv = *(const bf16x8*)&sB[cur][br*64 + kc*32 + kb];
          acc[rt*4+ct] = MFMA16(av,bv,acc[rt*4+ct]);
        }
      }
    }
    SOFT_BAR_LG();
  }
  int colg = lane&15, rowg=(lane>>4)*4;
  #pragma unroll
  for (int rt=0; rt<2; ++rt){
    #pragma unroll
    for (int ct=0; ct<4; ++ct){
      int col = bn + ct*16 + colg;
      float bv = bias[col];
      #pragma unroll
      for (int j=0;j<4;++j){
        int row = bm + (w*2+rt)*16 + rowg + j;
        if constexpr (OF32) ((float*)Ov)[(size_t)row*512 + col] = acc[rt*4+ct][j] + bv;
        else                ((u16*) Ov)[(size_t)row*512 + col] = f2bf(acc[rt*4+ct][j] + bv);
      }
    }
  }
}

// ---------------- k features + ctx partial: direct global->reg fragments, minimal LDS ----------------
// grid (8 h, 32 = s*8+mblk, 4 b); s owns n-range [s*512, (s+1)*512).
// Per chunk(64 n): K/V frags direct from global (L2-resident via h-XCD grouping); LDS only for kp^T bounce.
__global__ __launch_bounds__(256) void k_kpctx5(const u16* __restrict__ kB, const u16* __restrict__ projS,
    const u16* __restrict__ vT,
    float* __restrict__ ctxPT, float* __restrict__ kcsP, u32* __restrict__ kmaxEnc)
{
  int h=blockIdx.x, y=blockIdx.y, b=blockIdx.z;
  int mblk = y&7, s = y>>3;
  int bh=b*8+h;
  int m0 = mblk*64;
  __shared__ __align__(16) char pool[64*68*4];   // sT (u16 64x72=9216B) then sTf (f32 64x68=17408B)
  u16*  sT  = (u16*)pool;
  float* sTf = (float*)pool;
  __shared__ float sDg[64];
  __shared__ float sRed[4][64];
  __shared__ float red[4];
  int tid=threadIdx.x, w=tid>>6, lane=tid&63;
  int fr=lane&15, kbg=lane>>4, kb=kbg*8, rowg=kbg*4;
  // P fragments: loop-invariant (rows m0+mt*16+fr)
  bf16x8 pP[4][2];
  #pragma unroll
  for (int mt=0;mt<4;++mt)
    #pragma unroll
    for (int kc=0;kc<2;++kc)
      pP[mt][kc] = *(const bf16x8*)&projS[(size_t)(m0 + mt*16 + fr)*64 + kc*32 + kb];
  f32x4 accc[4]={};
  float sSr[4]={0.f,0.f,0.f,0.f};
  float lm=-3.0e38f;
  const u16* gK = kB + (size_t)(b*2048 + s*512)*512 + h*64;
  const u16* gV = vT + (size_t)bh*64*2048 + s*512;
  for (int nc=0; nc<8; ++nc){
    int n0=nc*64;
    // K fragments (A-operand rows n = n0 + w*16+fr)
    bf16x8 kf0 = *(const bf16x8*)&gK[(size_t)(n0 + w*16 + fr)*512 + kb];
    bf16x8 kf1 = *(const bf16x8*)&gK[(size_t)(n0 + w*16 + fr)*512 + 32 + kb];
    // V fragments (B-operand rows d = ct*16+fr, k=n-local)
    bf16x8 vf[4][2];
    #pragma unroll
    for (int ct=0;ct<4;++ct)
      #pragma unroll
      for (int ks=0;ks<2;++ks)
        vf[ct][ks] = *(const bf16x8*)&gV[(size_t)(ct*16+fr)*2048 + n0 + ks*32 + kb];
    // diag from K frags (wave-private region of sDg)
    {
      float sq=0.f;
      #pragma unroll
      for (int j=0;j<8;++j){ float f=bf2f((u16)kf0[j]); sq+=f*f; }
      #pragma unroll
      for (int j=0;j<8;++j){ float f=bf2f((u16)kf1[j]); sq+=f*f; }
      sq += __shfl_xor(sq,16,64); sq += __shfl_xor(sq,32,64);
      if (kbg==0) sDg[w*16 + fr] = 0.0625f*sq;
    }
    // feature MFMA: dd[64 n][64 m], wave w owns n rows w*16..+15
    f32x4 facc[4];
    #pragma unroll
    for (int mt=0;mt<4;++mt){
      f32x4 a={0.f,0.f,0.f,0.f};
      a = MFMA16(kf0, pP[mt][0], a);
      a = MFMA16(kf1, pP[mt][1], a);
      facc[mt]=a;
      lm=fmaxf(lm, fmaxf(fmaxf(a[0],a[1]),fmaxf(a[2],a[3])));
    }
    // exp -> sT[m][n] + S partial in regs
    {
      int nl = w*16 + rowg;
      #pragma unroll
      for (int mt=0;mt<4;++mt){
        int ml=mt*16+fr;
        s16x4 pk;
        #pragma unroll
        for (int j=0;j<4;++j){
          float vq = __expf(facc[mt][j]-sDg[nl+j]);
          u16 us = f2bf(vq);
          pk[j]=(short)us;
          sSr[mt] += bf2f(us);
        }
        *(s16x4*)&sT[ml*72+nl]=pk;
      }
    }
    SOFT_BAR_LG();   // publish sT
    // PV: ctx[m][d] += sT[m-rows][n] @ vf ; wave w owns m rows w*16..+15
    {
      int am=w*16+fr;
      bf16x8 a0 = *(const bf16x8*)&sT[am*72 + kb];
      bf16x8 a1 = *(const bf16x8*)&sT[am*72 + 32 + kb];
      #pragma unroll
      for (int ct=0;ct<4;++ct){
        accc[ct]=MFMA16(a0, vf[ct][0], accc[ct]);
        accc[ct]=MFMA16(a1, vf[ct][1], accc[ct]);
      }
    }
    SOFT_BAR_LG();   // retire sT reads before next chunk overwrites
  }
  // kmax partial + kcs partials + ctx bounce (single final barrier)
  #pragma unroll
  for (int m2=1;m2<64;m2<<=1) lm=fmaxf(lm,__shfl_xor(lm,m2,64));
  if (lane==0) red[w]=lm;
  #pragma unroll
  for (int mt=0;mt<4;++mt){
    float t=sSr[mt];
    t += __shfl_xor(t,16,64); t += __shfl_xor(t,32,64);
    if (kbg==0) sRed[w][mt*16+fr]=t;
  }
  {
    int mloc = w*16+rowg;
    #pragma unroll
    for (int ct=0;ct<4;++ct){
      #pragma unroll
      for (int j=0;j<4;++j) sTf[(ct*16+fr)*68 + mloc + j] = accc[ct][j];
    }
  }
  __syncthreads();
  if (tid==0) atomicMax(&kmaxEnc[bh], encf(fmaxf(fmaxf(red[0],red[1]),fmaxf(red[2],red[3]))));
  if (tid<64) kcsP[(size_t)(s*32+bh)*512 + m0 + tid] =
      sRed[0][tid]+sRed[1][tid]+sRed[2][tid]+sRed[3][tid];
  for (int u=tid; u<1024; u+=256){
    int r=u>>4, c=(u&15)*4;
    *(float4*)&ctxPT[((size_t)(s*32+bh)*64 + r)*512 + m0 + c] = *(const float4*)&sTf[r*68+c];
  }
}

// ---------------- combine 4 split-n partials -> ctxT bf16 + kcs ----------------
__global__ __launch_bounds__(256) void k_comb(const float* __restrict__ ctxPT, u16* __restrict__ ctxT,
                                              const float* __restrict__ kcsP, float* __restrict__ kcs){
  int bh=blockIdx.x, dblk=blockIdx.y;
  int tid=threadIdx.x;
  int d0=dblk*8;
  u16* o = ctxT + ((size_t)bh*64 + d0)*512;
  for (int u=tid; u<1024; u+=256){
    int r=u>>7, c=(u&127)*4;
    float4 a={0.f,0.f,0.f,0.f};
    #pragma unroll
    for (int s=0;s<4;++s){
      float4 p=*(const float4*)&ctxPT[((size_t)(s*32+bh)*64 + d0+r)*512 + c];
      a.x+=p.x; a.y+=p.y; a.z+=p.z; a.w+=p.w;
    }
    u16 t[4]={f2bf(a.x),f2bf(a.y),f2bf(a.z),f2bf(a.w)};
    *(int2*)&o[(size_t)r*512+c] = *(const int2*)t;
  }
  if (dblk==0){
    for (int u=tid; u<512; u+=256){
      float t=0.f;
      #pragma unroll
      for (int s=0;s<4;++s) t += kcsP[(size_t)(s*32+bh)*512+u];
      kcs[(size_t)bh*512+u]=t;
    }
  }
}

// ---------------- q features + PV + eps epilogue: direct global frags, BARRIER-FREE loop ----------------
// grid (8 h, 32 chunk, 4 b). qpL wave-private; P/ctxT fragments direct from global (L2-resident).
__global__ __launch_bounds__(256) void k_qpout4(const u16* __restrict__ qB, const u16* __restrict__ projS,
    const float* __restrict__ kcs, const u16* __restrict__ ctxT,
    const float* __restrict__ ctxsum, const float* __restrict__ kcssum,
    const float* __restrict__ vsum, const u32* __restrict__ kmaxEnc,
    u16* __restrict__ outc)
{
  int h=blockIdx.x, chunk=blockIdx.y, b=blockIdx.z;
  int bh=b*8+h;
  int t0 = b*2048 + chunk*64;
  __shared__ u16 qpL[64*72];
  __shared__ float sK[512];
  __shared__ float diag[64];
  int tid=threadIdx.x, w=tid>>6, lane=tid&63;
  int fr=lane&15, kbg=lane>>4, kb=kbg*8, rowg=kbg*4;
  bf16x8 qf[2];
  #pragma unroll
  for (int kc=0;kc<2;++kc)
    qf[kc] = *(const bf16x8*)&qB[(size_t)(t0 + w*16 + fr)*512 + h*64 + kc*32 + kb];
  {
    float ssum=0.f;
    #pragma unroll
    for (int kc=0;kc<2;++kc)
      #pragma unroll
      for (int j=0;j<8;++j){ float f=bf2f((u16)qf[kc][j]); ssum+=f*f; }
    ssum += __shfl_xor(ssum,16,64); ssum += __shfl_xor(ssum,32,64);
    if (kbg==0) diag[w*16 + fr] = 0.0625f*ssum;
  }
  for (int u=tid; u<512; u+=256) sK[u] = kcs[(size_t)bh*512 + u];
  __syncthreads();   // publish sK (diag is wave-private)
  const u16* gC = ctxT + (size_t)bh*64*512;
  f32x4 acc2[4]={};
  float mx[4], dp[4], rs[4];
  #pragma unroll
  for (int j=0;j<4;++j){ mx[j]=-3.0e38f; dp[j]=0.f; rs[j]=0.f; }
  for (int mc=0; mc<8; ++mc){
    // P fragments (B rows m = mc*64 + mt*16+fr)
    bf16x8 pf[4][2];
    #pragma unroll
    for (int mt=0;mt<4;++mt)
      #pragma unroll
      for (int kc=0;kc<2;++kc)
        pf[mt][kc] = *(const bf16x8*)&projS[(size_t)(mc*64 + mt*16 + fr)*64 + kc*32 + kb];
    // ctxT fragments (B rows d = ct*16+fr, k = m-local)
    bf16x8 cf[4][2];
    #pragma unroll
    for (int ct=0;ct<4;++ct)
      #pragma unroll
      for (int kc=0;kc<2;++kc)
        cf[ct][kc] = *(const bf16x8*)&gC[(size_t)(ct*16+fr)*512 + mc*64 + kc*32 + kb];
    // feature MFMA
    f32x4 facc[4];
    #pragma unroll
    for (int mt=0;mt<4;++mt){
      f32x4 a={0.f,0.f,0.f,0.f};
      a = MFMA16(qf[0], pf[mt][0], a);
      a = MFMA16(qf[1], pf[mt][1], a);
      facc[mt]=a;
    }
    // exp -> qpL (wave-private rows), dp/rs/mx
    #pragma unroll
    for (int mt=0;mt<4;++mt){
      float skv = sK[mc*64 + mt*16 + fr];
      #pragma unroll
      for (int j=0;j<4;++j){
        int rl = w*16 + rowg + j;
        mx[j] = fmaxf(mx[j], facc[mt][j]);
        float vq = __expf(facc[mt][j] - diag[rl]);
        u16 us = f2bf(vq);
        qpL[rl*72 + mt*16 + fr] = us;
        float uf = bf2f(us);
        dp[j] += uf*skv;
        rs[j] += uf;
      }
    }
    // PV (same-wave qpL; compiler inserts lgkmcnt — no block barrier needed)
    {
      bf16x8 a0 = *(const bf16x8*)&qpL[(w*16+fr)*72 + kb];
      bf16x8 a1 = *(const bf16x8*)&qpL[(w*16+fr)*72 + 32 + kb];
      #pragma unroll
      for (int ct=0;ct<4;++ct){
        acc2[ct] = MFMA16(a0, cf[ct][0], acc2[ct]);
        acc2[ct] = MFMA16(a1, cf[ct][1], acc2[ct]);
      }
    }
  }
  #pragma unroll
  for (int j=0;j<4;++j){
    #pragma unroll
    for (int s=1;s<16;s<<=1){
      dp[j] += __shfl_xor(dp[j],s,64);
      rs[j] += __shfl_xor(rs[j],s,64);
      mx[j]  = fmaxf(mx[j], __shfl_xor(mx[j],s,64));
    }
  }
  float mk  = decf(kmaxEnc[bh]);
  float emk = __expf(mk);
  float Ssum = kcssum[bh];
  const float eps=1e-4f;
  float emq[4];
  #pragma unroll
  for (int j=0;j<4;++j) emq[j]=__expf(mx[j]);
  #pragma unroll
  for (int ct=0;ct<4;++ct){
    int d = ct*16 + fr;
    float cs = ctxsum[bh*64 + d];
    float vs = vsum[bh*64 + d];
    #pragma unroll
    for (int j=0;j<4;++j){
      float eq = emq[j];
      float numer = acc2[ct][j] + eps*(emk*vs*rs[j] + eq*cs + eps*eq*emk*512.0f*vs);
      float den   = dp[j]       + eps*(emk*2048.0f*rs[j] + eq*Ssum + eps*eq*emk*512.0f*2048.0f);
      int row = t0 + w*16 + rowg + j;
      outc[(size_t)row*512 + h*64 + d] = f2bf(numer/den);
    }
  }
}

extern "C" void kernel_launch(void* const* d_in, const int* in_sizes, int n_in,
                              void* d_out, int out_size, void* d_ws, size_t ws_size,
                              hipStream_t stream)
{
  (void)in_sizes; (void)n_in; (void)out_size; (void)ws_size;
  const float* x    = (const float*)d_in[0];
  const float* Wq   = (const float*)d_in[1];
  const float* bq   = (const float*)d_in[2];
  const float* Wk   = (const float*)d_in[3];
  const float* bk   = (const float*)d_in[4];
  const float* Wv   = (const float*)d_in[5];
  const float* bv   = (const float*)d_in[6];
  const float* Wo   = (const float*)d_in[7];
  const float* bo   = (const float*)d_in[8];
  const float* proj = (const float*)d_in[9];

  char* w = (char*)d_ws;
  size_t off=0;
  auto alloc=[&](size_t bytes)->char*{ char* p=w+off; off=(off+bytes+255)&~(size_t)255; return p; };
  u16*  xb   = (u16*)alloc(8192ull*512*2);
  u16*  qB   = (u16*)alloc(8192ull*512*2);
  u16*  kBf  = (u16*)alloc(8192ull*512*2);
  u16*  vB   = (u16*)alloc(8192ull*512*2);
  u16*  vT   = (u16*)alloc(32ull*64*2048*2);
  u16*  WqT  = (u16*)alloc(512ull*512*2);
  u16*  WkT  = (u16*)alloc(512ull*512*2);
  u16*  WvT  = (u16*)alloc(512ull*512*2);
  u16*  WoT  = (u16*)alloc(512ull*512*2);
  u16*  projS= (u16*)alloc(512ull*64*2);
  u16*  ctxT = (u16*)alloc(32ull*64*512*2);
  float* ctxPT=(float*)alloc(4ull*32*64*512*4);
  float* kcs = (float*)alloc(32ull*512*4);
  float* kcsP= (float*)alloc(4ull*32*512*4);
  u32*  kmx  = (u32*)alloc(256);
  float* ctxs= (float*)alloc(32ull*64*4);
  float* kcss= (float*)alloc(32ull*4);
  float* vsm = (float*)alloc(32ull*64*4);
  u16*  outc = kBf;  // kBf dead after k_kpctx5; reuse

  dim3 TB(256);
  k_init<<<dim3(256),TB,0,stream>>>(kmx,projS,proj,x,xb);
  k_trw<<<dim3(16,16,4),TB,0,stream>>>(Wq,Wk,Wv,Wo, WqT,WkT,WvT,WoT);
  k_gemm2<false><<<dim3(64,8,3),TB,0,stream>>>(xb, WqT,WkT,WvT, bq,bk,bv, qB,kBf,vB);
  k_trv<<<dim3(2,64,32),TB,0,stream>>>(vB, vT);
  k_vsum<<<dim3(32),TB,0,stream>>>(vB, vsm);
  k_kpctx5<<<dim3(8,32,4),TB,0,stream>>>(kBf, projS, vT, ctxPT, kcsP, kmx);
  k_comb<<<dim3(32,8),TB,0,stream>>>(ctxPT, ctxT, kcsP, kcs);
  k_sums<<<dim3(32),TB,0,stream>>>(ctxT, kcs, ctxs, kcss);
  k_qpout4<<<dim3(8,32,4),TB,0,stream>>>(qB, projS, kcs, ctxT, ctxs, kcss, vsm, kmx, outc);
  k_gemm2<true><<<dim3(64,8,1),TB,0,stream>>>(outc, WoT,WoT,WoT, bo,bo,bo,
                                              d_out,d_out,d_out);
}

// Round 11
// 147.647 us; speedup vs baseline: 1.3669x; 1.3669x over previous
//
#include <hip/hip_runtime.h>

typedef unsigned short u16;
typedef unsigned int   u32;
typedef __attribute__((ext_vector_type(8))) short bf16x8;
typedef __attribute__((ext_vector_type(4))) short s16x4;
typedef __attribute__((ext_vector_type(4))) float f32x4;

#define MFMA16(a,b,c) __builtin_amdgcn_mfma_f32_16x16x32_bf16((a),(b),(c),0,0,0)

__device__ __forceinline__ float bf2f(u16 u){ return __uint_as_float(((u32)u)<<16); }
__device__ __forceinline__ u16 f2bf(float f){
  u32 u = __float_as_uint(f);
  return (u16)((u + 0x7fffu + ((u>>16)&1u)) >> 16);
}
__device__ __forceinline__ u32 encf(float f){ u32 u=__float_as_uint(f); return (u&0x80000000u)? ~u : (u|0x80000000u); }
__device__ __forceinline__ float decf(u32 u){ return (u&0x80000000u)? __uint_as_float(u&0x7fffffffu) : __uint_as_float(~u); }

__device__ __forceinline__ void async_lds16(u16* lds, const u16* g){
  __builtin_amdgcn_global_load_lds((const __attribute__((address_space(1))) void*)g,
                                   (__attribute__((address_space(3))) void*)lds,
                                   16, 0, 0);
}

// stage ROWS x 64 bf16 from global into LDS padded to 72/row
template<int ROWS>
__device__ __forceinline__ void stage64(u16* dst, const u16* src, int srcStride, int tid){
  #pragma unroll
  for (int u=tid; u<ROWS*8; u+=256){
    int r=u>>3, c=(u&7)<<3;
    *(int4*)&dst[r*72+c] = *(const int4*)&src[(size_t)r*srcStride + c];
  }
}

// ---------------- setup: weight transposes (blocks 0..1023) + init/cast (blocks 1024..1279) ----------------
__global__ __launch_bounds__(256) void k_setup(u32* kmaxEnc, u16* projS,
    const float* __restrict__ proj, const float* __restrict__ x, u16* __restrict__ xb,
    const float* s0, const float* s1, const float* s2, const float* s3,
    u16* d0, u16* d1, u16* d2, u16* d3)
{
  int bid=blockIdx.x, tid=threadIdx.x;
  if (bid < 1024){
    int z = bid>>8, t = bid&255;
    const float* src = z==0?s0:(z==1?s1:(z==2?s2:s3));
    u16* dst         = z==0?d0:(z==1?d1:(z==2?d2:d3));
    __shared__ u16 tl[32][34];
    int c0=(t&15)*32, r0=(t>>4)*32;
    for (int u=tid; u<1024; u+=256){ int r=u>>5, c=u&31; tl[r][c]=f2bf(src[(size_t)(r0+r)*512 + c0+c]); }
    __syncthreads();
    for (int u=tid; u<1024; u+=256){ int c=u>>5, r=u&31; dst[(size_t)(c0+c)*512 + r0+r]=tl[r][c]; }
  } else {
    int i = (bid-1024)*256 + tid;
    int st = 256*256;
    for (int j=i; j<32; j+=st) kmaxEnc[j]=0u;
    const float dn = 0.35355339059327373f; // 64^-0.25
    for (int j=i; j<512*64; j+=st) projS[j] = f2bf(dn*proj[j]);
    for (int j=i; j<524288; j+=st){
      float4 a = *(const float4*)&x[(size_t)j*8];
      float4 b = *(const float4*)&x[(size_t)j*8+4];
      u16 tmp[8] = {f2bf(a.x),f2bf(a.y),f2bf(a.z),f2bf(a.w),
                    f2bf(b.x),f2bf(b.y),f2bf(b.z),f2bf(b.w)};
      *(int4*)&xb[(size_t)j*8] = *(const int4*)tmp;
    }
  }
}

// ---------------- prep: trv (0..4095) + vsum (4096..4127) + kdiag (4128..4383) ----------------
__global__ __launch_bounds__(256) void k_prep(const u16* __restrict__ vB, u16* __restrict__ vT,
    float* __restrict__ vsum, const u16* __restrict__ kB, float* __restrict__ diagK)
{
  int bid=blockIdx.x, tid=threadIdx.x;
  if (bid < 4096){
    int xx=bid&1, y=(bid>>1)&63, bh=bid>>7;
    int b=bh>>3, h=bh&7;
    int dd0=xx*32, n0=y*32;
    __shared__ u16 t[32][34];
    const u16* s = vB + (size_t)(b*2048)*512 + h*64;
    for (int u=tid; u<1024; u+=256){ int r=u>>5, c=u&31; t[r][c]=s[(size_t)(n0+r)*512 + dd0+c]; }
    __syncthreads();
    u16* d = vT + (size_t)bh*64*2048;
    for (int u=tid; u<1024; u+=256){ int c=u>>5, r=u&31; d[(size_t)(dd0+c)*2048 + n0+r]=t[r][c]; }
  } else if (bid < 4128){
    int bh=bid-4096; int b=bh>>3, h=bh&7;
    int d=tid&63, part=tid>>6;
    const u16* src = vB + (size_t)(b*2048 + part*512)*512 + h*64 + d;
    float s=0.f;
    for (int n=0;n<512;++n) s += bf2f(src[(size_t)n*512]);
    __shared__ float red[256];
    red[tid]=s; __syncthreads();
    if (part==0) vsum[bh*64+d]=red[d]+red[64+d]+red[128+d]+red[192+d];
  } else {
    int idx=bid-4128;
    int bh=idx&31, seg=idx>>5;
    int b=bh>>3, h=bh&7;
    int part=tid&7;
    const u16* base = kB + (size_t)(b*2048 + seg*256)*512 + h*64 + part*8;
    for (int n0=0; n0<256; n0+=32){
      int n = n0 + (tid>>3);
      bf16x8 v = *(const bf16x8*)&base[(size_t)n*512];
      float sq=0.f;
      #pragma unroll
      for (int j=0;j<8;++j){ float f=bf2f((u16)v[j]); sq+=f*f; }
      sq += __shfl_xor(sq,1,64); sq += __shfl_xor(sq,2,64); sq += __shfl_xor(sq,4,64);
      if (part==0) diagK[(size_t)bh*2048 + seg*256 + n] = 0.0625f*sq;
    }
  }
}

// ---------------- GEMM m97-style (round-6 proven): O[8192x512] = A(bf16) @ BT^T + bias ----------------
template<bool OF32>
__global__ __launch_bounds__(256) void k_gemm2(const u16* __restrict__ A,
    const u16* BT0, const u16* BT1, const u16* BT2,
    const float* b0, const float* b1, const float* b2,
    void* O0, void* O1, void* O2)
{
  int z = blockIdx.z;
  const u16* BT    = z==0?BT0:(z==1?BT1:BT2);
  const float* bias= z==0?b0 :(z==1?b1 :b2 );
  void* Ov         = z==0?O0 :(z==1?O1 :O2 );
  int bm = blockIdx.x*128, bn = blockIdx.y*64;
  __shared__ u16 sA[128*64];
  __shared__ u16 sB[64*64];
  int tid=threadIdx.x, w=tid>>6, lane=tid&63;
  int lr = lane>>3, lc = (lane&7)*8;
  f32x4 acc[8] = {};
  for (int kk=0; kk<512; kk+=64){
    __syncthreads();
    #pragma unroll
    for (int i=0;i<4;++i){
      int idx = w*4+i;
      async_lds16(&sA[idx*512], A + (size_t)(bm + idx*8 + lr)*512 + kk + lc);
    }
    #pragma unroll
    for (int i=0;i<2;++i){
      int idx = w*2+i;
      async_lds16(&sB[idx*512], BT + (size_t)(bn + idx*8 + lr)*512 + kk + lc);
    }
    __syncthreads();
    int fr = lane&15, kb=(lane>>4)*8;
    #pragma unroll
    for (int rt=0; rt<2; ++rt){
      int ar = (w*2+rt)*16 + fr;
      #pragma unroll
      for (int ct=0; ct<4; ++ct){
        int br = ct*16 + fr;
        #pragma unroll
        for (int kc=0; kc<2; ++kc){
          bf16x8 av = *(const bf16x8*)&sA[ar*64 + kc*32 + kb];
          bf16x8 bv = *(const bf16x8*)&sB[br*64 + kc*32 + kb];
          acc[rt*4+ct] = MFMA16(av,bv,acc[rt*4+ct]);
        }
      }
    }
  }
  int colg = lane&15, rowg=(lane>>4)*4;
  #pragma unroll
  for (int rt=0; rt<2; ++rt){
    #pragma unroll
    for (int ct=0; ct<4; ++ct){
      int col = bn + ct*16 + colg;
      float bv = bias[col];
      #pragma unroll
      for (int j=0;j<4;++j){
        int row = bm + (w*2+rt)*16 + rowg + j;
        if constexpr (OF32) ((float*)Ov)[(size_t)row*512 + col] = acc[rt*4+ct][j] + bv;
        else                ((u16*) Ov)[(size_t)row*512 + col] = f2bf(acc[rt*4+ct][j] + bv);
      }
    }
  }
}

// ---------------- k features (exp-only) + half-n ctx partial + S (in-reg) + mk ----------------
// round-6 structure; S accumulated in registers during exp (no per-chunk scalar LDS reads).
__global__ __launch_bounds__(256) void k_kpctx3(const u16* __restrict__ kB, const u16* __restrict__ projS,
    const u16* __restrict__ vT, const float* __restrict__ diagK,
    float* __restrict__ ctxPT, float* __restrict__ kcsP, u32* __restrict__ kmaxEnc)
{
  int h=blockIdx.x, y=blockIdx.y, b=blockIdx.z;
  int mblk = y&7, s = y>>3;
  int bh=b*8+h;
  int m0 = mblk*64;
  __shared__ __align__(16) u16 sK[128*72];
  __shared__ __align__(16) u16 sV[64*136];
  __shared__ __align__(16) u16 sP[64*72];
  __shared__ __align__(16) u16 sT[64*136];
  __shared__ float sDg[128];
  __shared__ float red[4];
  __shared__ float sRed[4][64];
  int tid=threadIdx.x, w=tid>>6, lane=tid&63;
  int fr=lane&15, kbg=lane>>4, kb=kbg*8, rowg=kbg*4;
  stage64<64>(sP, projS + m0*64, 64, tid);
  f32x4 accc[4]={};
  float sSm[4]={0.f,0.f,0.f,0.f};   // per-thread S partial for m = mt*16+fr
  float lm=-3.0e38f;
  const u16* gK = kB + (size_t)(b*2048 + s*1024)*512 + h*64;
  const u16* gV = vT + (size_t)bh*64*2048 + s*1024;
  const float* gD = diagK + (size_t)bh*2048 + s*1024;
  int4 pK[4], pV[4]; float4 pD={0.f,0.f,0.f,0.f};
  #pragma unroll
  for (int i=0;i<4;++i){ int u=tid+i*256; int r=u>>3,c=(u&7)<<3; pK[i]=*(const int4*)&gK[(size_t)r*512 + c]; }
  #pragma unroll
  for (int i=0;i<4;++i){ int u=tid+i*256; int r=u>>4,c=(u&15)<<3; pV[i]=*(const int4*)&gV[(size_t)r*2048 + c]; }
  if (tid<32) pD = *(const float4*)&gD[tid*4];
  for (int nc=0; nc<8; ++nc){
    #pragma unroll
    for (int i=0;i<4;++i){ int u=tid+i*256; int r=u>>3,c=(u&7)<<3; *(int4*)&sK[r*72+c]=pK[i]; }
    #pragma unroll
    for (int i=0;i<4;++i){ int u=tid+i*256; int r=u>>4,c=(u&15)<<3; *(int4*)&sV[r*136+c]=pV[i]; }
    if (tid<32) *(float4*)&sDg[tid*4] = pD;
    __syncthreads();
    if (nc<7){
      #pragma unroll
      for (int i=0;i<4;++i){ int u=tid+i*256; int r=u>>3,c=(u&7)<<3; pK[i]=*(const int4*)&gK[(size_t)((nc+1)*128+r)*512 + c]; }
      #pragma unroll
      for (int i=0;i<4;++i){ int u=tid+i*256; int r=u>>4,c=(u&15)<<3; pV[i]=*(const int4*)&gV[(size_t)r*2048 + (nc+1)*128 + c]; }
      if (tid<32) pD = *(const float4*)&gD[(nc+1)*128 + tid*4];
    }
    // feature MFMA: dd[128 n][64 m]
    f32x4 facc[2][4];
    #pragma unroll
    for (int rt=0;rt<2;++rt){
      int ar=(w*2+rt)*16+fr;
      #pragma unroll
      for (int mt=0;mt<4;++mt){
        f32x4 a={0.f,0.f,0.f,0.f};
        a=MFMA16(*(const bf16x8*)&sK[ar*72+kb],    *(const bf16x8*)&sP[(mt*16+fr)*72+kb],    a);
        a=MFMA16(*(const bf16x8*)&sK[ar*72+32+kb], *(const bf16x8*)&sP[(mt*16+fr)*72+32+kb], a);
        facc[rt][mt]=a;
        lm=fmaxf(lm, fmaxf(fmaxf(a[0],a[1]),fmaxf(a[2],a[3])));
      }
    }
    // exp -> sT[m][n], S accumulated in regs
    #pragma unroll
    for (int rt=0;rt<2;++rt){
      int nl=(w*2+rt)*16+rowg;
      #pragma unroll
      for (int mt=0;mt<4;++mt){
        int ml=mt*16+fr;
        s16x4 pk;
        #pragma unroll
        for (int j=0;j<4;++j){
          float vk = __expf(facc[rt][mt][j]-sDg[nl+j]);
          u16 us = f2bf(vk);
          pk[j]=(short)us;
          sSm[mt] += bf2f(us);
        }
        *(s16x4*)&sT[ml*136+nl]=pk;
      }
    }
    __syncthreads();
    // PV MFMA
    int am=w*16+fr;
    #pragma unroll
    for (int ct=0;ct<4;++ct){
      #pragma unroll
      for (int ks=0;ks<4;++ks){
        accc[ct]=MFMA16(*(const bf16x8*)&sT[am*136+ks*32+kb],
                        *(const bf16x8*)&sV[(ct*16+fr)*136+ks*32+kb], accc[ct]);
      }
    }
    __syncthreads();
  }
  // S reduce: across kbg groups (same w, same fr), store per-w partial
  #pragma unroll
  for (int mt=0;mt<4;++mt){
    float t=sSm[mt];
    t += __shfl_xor(t,16,64); t += __shfl_xor(t,32,64);
    if (kbg==0) sRed[w][mt*16+fr]=t;
  }
  // mk partial
  #pragma unroll
  for (int m2=1;m2<64;m2<<=1) lm=fmaxf(lm,__shfl_xor(lm,m2,64));
  if (lane==0) red[w]=lm;
  // ctx partial f32, transposed [d][m] via LDS bounce (reuse sT as float[64][68])
  float* sTf = (float*)sT;
  int mloc = w*16+rowg;
  #pragma unroll
  for (int ct=0;ct<4;++ct){
    #pragma unroll
    for (int j=0;j<4;++j) sTf[(ct*16+fr)*68 + mloc + j] = accc[ct][j];
  }
  __syncthreads();
  if (tid==0) atomicMax(&kmaxEnc[bh], encf(fmaxf(fmaxf(red[0],red[1]),fmaxf(red[2],red[3]))));
  if (tid<64) kcsP[(size_t)(s*32+bh)*512 + m0 + tid] =
      sRed[0][tid]+sRed[1][tid]+sRed[2][tid]+sRed[3][tid];
  for (int u=tid; u<1024; u+=256){
    int r=u>>4, c=(u&15)*4;
    *(float4*)&ctxPT[((size_t)(s*32+bh)*64 + r)*512 + m0 + c] = *(const float4*)&sTf[r*68+c];
  }
}

// ---------------- combine split-n partials -> ctxT bf16 + kcs, fused ctxsum/kcssum ----------------
__global__ __launch_bounds__(256) void k_comb2(const float* __restrict__ ctxPT, u16* __restrict__ ctxT,
    const float* __restrict__ kcsP, float* __restrict__ kcs,
    float* __restrict__ ctxsum, float* __restrict__ kcssum)
{
  int bh=blockIdx.x, dblk=blockIdx.y;
  int tid=threadIdx.x;
  int d0=dblk*8;
  __shared__ float sDsum[8];
  __shared__ float sKsum[256];
  if (tid<8) sDsum[tid]=0.f;
  __syncthreads();
  const float* p0 = ctxPT + ((size_t)bh*64 + d0)*512;
  const float* p1 = ctxPT + ((size_t)(32+bh)*64 + d0)*512;
  u16* o = ctxT + ((size_t)bh*64 + d0)*512;
  for (int u=tid; u<1024; u+=256){
    int r=u>>7, c=(u&127)*4;
    float4 a=*(const float4*)&p0[(size_t)r*512+c];
    float4 bq=*(const float4*)&p1[(size_t)r*512+c];
    float vx=a.x+bq.x, vy=a.y+bq.y, vz=a.z+bq.z, vw=a.w+bq.w;
    u16 t[4]={f2bf(vx),f2bf(vy),f2bf(vz),f2bf(vw)};
    *(int2*)&o[(size_t)r*512+c] = *(const int2*)t;
    // use bf16-rounded values for the sum (matches prior k_sums numerics)
    atomicAdd(&sDsum[r], bf2f(t[0])+bf2f(t[1])+bf2f(t[2])+bf2f(t[3]));
  }
  float tpart=0.f;
  if (dblk==0){
    for (int u=tid; u<512; u+=256){
      float t = kcsP[(size_t)bh*512+u] + kcsP[(size_t)(32+bh)*512+u];
      kcs[(size_t)bh*512+u]=t;
      tpart += t;
    }
  }
  sKsum[tid]=tpart;
  __syncthreads();
  if (tid<8) ctxsum[bh*64 + d0 + tid] = sDsum[tid];
  if (dblk==0 && tid<64){
    float a=sKsum[tid]+sKsum[tid+64]+sKsum[tid+128]+sKsum[tid+192];
    #pragma unroll
    for (int m2=1;m2<64;m2<<=1) a += __shfl_xor(a,m2,64);
    if (tid==0) kcssum[bh]=a;
  }
}

// ---------------- q features (exp-only) + PV + exact eps epilogue (round-6 proven) ----------------
__global__ __launch_bounds__(256) void k_qpout2(const u16* __restrict__ qB, const u16* __restrict__ projS,
    const float* __restrict__ kcs, const u16* __restrict__ ctxT,
    const float* __restrict__ ctxsum, const float* __restrict__ kcssum,
    const float* __restrict__ vsum, const u32* __restrict__ kmaxEnc,
    u16* __restrict__ outc)
{
  int h=blockIdx.x, chunk=blockIdx.y, b=blockIdx.z;
  int bh=b*8+h;
  int t0 = b*2048 + chunk*128;
  __shared__ u16 sP[2][64*64];
  __shared__ u16 sCt[2][64*64];
  __shared__ u16 qpL[128*72];
  __shared__ float sK[512];
  __shared__ float diag[128];
  int tid=threadIdx.x, w=tid>>6, lane=tid&63;
  int fr=lane&15, kb=(lane>>4)*8, rowg=(lane>>4)*4;
  bf16x8 qf[2][2];
  #pragma unroll
  for (int rt=0;rt<2;++rt)
    #pragma unroll
    for (int kc=0;kc<2;++kc)
      qf[rt][kc] = *(const bf16x8*)&qB[(size_t)(t0 + w*32 + rt*16 + fr)*512 + h*64 + kc*32 + kb];
  #pragma unroll
  for (int rt=0;rt<2;++rt){
    float s=0.f;
    #pragma unroll
    for (int kc=0;kc<2;++kc)
      #pragma unroll
      for (int j=0;j<8;++j){ float f=bf2f((u16)qf[rt][kc][j]); s+=f*f; }
    s += __shfl_xor(s,16,64); s += __shfl_xor(s,32,64);
    if (lane<16) diag[w*32 + rt*16 + fr] = 0.0625f*s;
  }
  for (int u=tid; u<512; u+=256) sK[u] = kcs[(size_t)bh*512 + u];
  {
    const u16* gp = projS;
    const u16* gc = ctxT + (size_t)bh*64*512;
    int lr=lane>>3, lc=(lane&7)*8;
    #pragma unroll
    for (int i=0;i<2;++i){
      int idx = w*2+i;
      async_lds16(&sP[0][idx*512], gp + idx*512 + lane*8);
      async_lds16(&sCt[0][idx*512], gc + (size_t)(idx*8+lr)*512 + lc);
    }
  }
  f32x4 acc2[2][4]={};
  float mx[2][4], dp[2][4], rs[2][4];
  #pragma unroll
  for (int rt=0;rt<2;++rt)
    #pragma unroll
    for (int j=0;j<4;++j){ mx[rt][j]=-3.0e38f; dp[rt][j]=0.f; rs[rt][j]=0.f; }
  __syncthreads();
  for (int mc=0; mc<8; ++mc){
    int cur = mc&1;
    if (mc<7){
      int nxt = cur^1;
      const u16* gp = projS + (mc+1)*64*64;
      const u16* gc = ctxT + (size_t)bh*64*512 + (mc+1)*64;
      int lr=lane>>3, lc=(lane&7)*8;
      #pragma unroll
      for (int i=0;i<2;++i){
        int idx = w*2+i;
        async_lds16(&sP[nxt][idx*512], gp + idx*512 + lane*8);
        async_lds16(&sCt[nxt][idx*512], gc + (size_t)(idx*8+lr)*512 + lc);
      }
    }
    f32x4 facc[2][4];
    #pragma unroll
    for (int rt=0;rt<2;++rt){
      #pragma unroll
      for (int mt=0;mt<4;++mt){
        f32x4 a={0.f,0.f,0.f,0.f};
        #pragma unroll
        for (int kc=0;kc<2;++kc){
          bf16x8 bv = *(const bf16x8*)&sP[cur][(mt*16+fr)*64 + kc*32 + kb];
          a = MFMA16(qf[rt][kc], bv, a);
        }
        facc[rt][mt]=a;
      }
    }
    #pragma unroll
    for (int rt=0;rt<2;++rt){
      #pragma unroll
      for (int mt=0;mt<4;++mt){
        #pragma unroll
        for (int j=0;j<4;++j){
          int rl = w*32 + rt*16 + rowg + j;
          mx[rt][j] = fmaxf(mx[rt][j], facc[rt][mt][j]);
          float vq = __expf(facc[rt][mt][j] - diag[rl]);
          u16 us = f2bf(vq);
          qpL[rl*72 + mt*16 + fr] = us;
          float uf = bf2f(us);
          dp[rt][j] += uf*sK[mc*64 + mt*16 + fr];
          rs[rt][j] += uf;
        }
      }
    }
    __syncthreads();
    #pragma unroll
    for (int rt=0;rt<2;++rt){
      #pragma unroll
      for (int ct=0;ct<4;++ct){
        #pragma unroll
        for (int kc=0;kc<2;++kc){
          bf16x8 av = *(const bf16x8*)&qpL[(w*32+rt*16+fr)*72 + kc*32 + kb];
          bf16x8 bv = *(const bf16x8*)&sCt[cur][(ct*16+fr)*64 + kc*32 + kb];
          acc2[rt][ct] = MFMA16(av,bv,acc2[rt][ct]);
        }
      }
    }
    __syncthreads();
  }
  #pragma unroll
  for (int rt=0;rt<2;++rt){
    #pragma unroll
    for (int j=0;j<4;++j){
      #pragma unroll
      for (int s=1;s<16;s<<=1){
        dp[rt][j] += __shfl_xor(dp[rt][j],s,64);
        rs[rt][j] += __shfl_xor(rs[rt][j],s,64);
        mx[rt][j]  = fmaxf(mx[rt][j], __shfl_xor(mx[rt][j],s,64));
      }
    }
  }
  float mk  = decf(kmaxEnc[bh]);
  float emk = __expf(mk);
  float Ssum = kcssum[bh];
  const float eps=1e-4f;
  float emq[2][4];
  #pragma unroll
  for (int rt=0;rt<2;++rt)
    #pragma unroll
    for (int j=0;j<4;++j) emq[rt][j]=__expf(mx[rt][j]);
  #pragma unroll
  for (int rt=0;rt<2;++rt){
    #pragma unroll
    for (int ct=0;ct<4;++ct){
      int d = ct*16 + fr;
      float cs = ctxsum[bh*64 + d];
      float vs = vsum[bh*64 + d];
      #pragma unroll
      for (int j=0;j<4;++j){
        float eq = emq[rt][j];
        float numer = acc2[rt][ct][j] + eps*(emk*vs*rs[rt][j] + eq*cs + eps*eq*emk*512.0f*vs);
        float den   = dp[rt][j]       + eps*(emk*2048.0f*rs[rt][j] + eq*Ssum + eps*eq*emk*512.0f*2048.0f);
        int row = t0 + w*32 + rt*16 + rowg + j;
        outc[(size_t)row*512 + h*64 + d] = f2bf(numer/den);
      }
    }
  }
}

extern "C" void kernel_launch(void* const* d_in, const int* in_sizes, int n_in,
                              void* d_out, int out_size, void* d_ws, size_t ws_size,
                              hipStream_t stream)
{
  (void)in_sizes; (void)n_in; (void)out_size; (void)ws_size;
  const float* x    = (const float*)d_in[0];
  const float* Wq   = (const float*)d_in[1];
  const float* bq   = (const float*)d_in[2];
  const float* Wk   = (const float*)d_in[3];
  const float* bk   = (const float*)d_in[4];
  const float* Wv   = (const float*)d_in[5];
  const float* bv   = (const float*)d_in[6];
  const float* Wo   = (const float*)d_in[7];
  const float* bo   = (const float*)d_in[8];
  const float* proj = (const float*)d_in[9];

  char* w = (char*)d_ws;
  size_t off=0;
  auto alloc=[&](size_t bytes)->char*{ char* p=w+off; off=(off+bytes+255)&~(size_t)255; return p; };
  u16*  xb   = (u16*)alloc(8192ull*512*2);
  u16*  qB   = (u16*)alloc(8192ull*512*2);
  u16*  kBf  = (u16*)alloc(8192ull*512*2);
  u16*  vB   = (u16*)alloc(8192ull*512*2);
  u16*  vT   = (u16*)alloc(32ull*64*2048*2);
  u16*  WqT  = (u16*)alloc(512ull*512*2);
  u16*  WkT  = (u16*)alloc(512ull*512*2);
  u16*  WvT  = (u16*)alloc(512ull*512*2);
  u16*  WoT  = (u16*)alloc(512ull*512*2);
  u16*  projS= (u16*)alloc(512ull*64*2);
  u16*  ctxT = (u16*)alloc(32ull*64*512*2);
  float* ctxPT=(float*)alloc(2ull*32*64*512*4);
  float* kcs = (float*)alloc(32ull*512*4);
  float* kcsP= (float*)alloc(2ull*32*512*4);
  float* diagK=(float*)alloc(32ull*2048*4);
  u32*  kmx  = (u32*)alloc(256);
  float* ctxs= (float*)alloc(32ull*64*4);
  float* kcss= (float*)alloc(32ull*4);
  float* vsm = (float*)alloc(32ull*64*4);
  u16*  outc = kBf;  // kBf dead after k_kpctx3; reuse

  dim3 TB(256);
  k_setup<<<dim3(1280),TB,0,stream>>>(kmx,projS,proj,x,xb, Wq,Wk,Wv,Wo, WqT,WkT,WvT,WoT);
  k_gemm2<false><<<dim3(64,8,3),TB,0,stream>>>(xb, WqT,WkT,WvT, bq,bk,bv, qB,kBf,vB);
  k_prep<<<dim3(4384),TB,0,stream>>>(vB, vT, vsm, kBf, diagK);
  k_kpctx3<<<dim3(8,16,4),TB,0,stream>>>(kBf, projS, vT, diagK, ctxPT, kcsP, kmx);
  k_comb2<<<dim3(32,8),TB,0,stream>>>(ctxPT, ctxT, kcsP, kcs, ctxs, kcss);
  k_qpout2<<<dim3(8,16,4),TB,0,stream>>>(qB, projS, kcs, ctxT, ctxs, kcss, vsm, kmx, outc);
  k_gemm2<true><<<dim3(64,8,1),TB,0,stream>>>(outc, WoT,WoT,WoT, bo,bo,bo,
                                              d_out,d_out,d_out);
}